// Round 3
// baseline (109.101 us; speedup 1.0000x reference)
//
#include <hip/hip_runtime.h>

// RandomAffine: bilinear warp of (2048,2048,3) f32 image, mode='reflect'.
// Output pixel (i,j,c):
//   yv = -1024 + i*2048/2047 ; xv = -1024 + j*2048/2047
//   ry = yv*M[0] + xv*M[3] + M[6] + 1024
//   rx = yv*M[1] + xv*M[4] + M[7] + 1024
//   bilinear sample of channel c at (ry, rx) with reflect index fixing.

#define IMG_H 2048
#define IMG_W 2048

__device__ __forceinline__ int reflect2048(int i) {
    // scipy-documented 'reflect': period 2n, duplicate edges.
    // n = 2048 (power of two): p = i mod 4096 via mask (works for negatives).
    int p = i & 4095;
    return (p < 2048) ? p : (4095 - p);
}

__global__ __launch_bounds__(256) void affine_reflect_kernel(
    const float* __restrict__ img, const float* __restrict__ M,
    float* __restrict__ out)
{
    int idx = blockIdx.x * 256 + threadIdx.x;   // one output pixel (all 3 ch)
    int i = idx >> 11;          // row
    int j = idx & 2047;         // col

    const float step = 2048.0f / 2047.0f;
    float yv = fmaf((float)i, step, -1024.0f);
    float xv = fmaf((float)j, step, -1024.0f);

    float m00 = M[0], m01 = M[1];
    float m10 = M[3], m11 = M[4];
    float m20 = M[6], m21 = M[7];

    float ry = yv * m00 + xv * m10 + (m20 + 1024.0f);
    float rx = yv * m01 + xv * m11 + (m21 + 1024.0f);

    float fy = floorf(ry), fx = floorf(rx);
    float wy1 = ry - fy, wx1 = rx - fx;
    float wy0 = 1.0f - wy1, wx0 = 1.0f - wx1;

    int iy = (int)fy, ix = (int)fx;
    int iy0 = reflect2048(iy),     iy1 = reflect2048(iy + 1);
    int ix0 = reflect2048(ix),     ix1 = reflect2048(ix + 1);

    const float* r0 = img + iy0 * (IMG_W * 3);
    const float* r1 = img + iy1 * (IMG_W * 3);
    int c0 = ix0 * 3, c1 = ix1 * 3;

    float w00 = wy0 * wx0, w01 = wy0 * wx1;
    float w10 = wy1 * wx0, w11 = wy1 * wx1;

    int o = idx * 3;
    #pragma unroll
    for (int c = 0; c < 3; ++c) {
        float v = w00 * r0[c0 + c] + w01 * r0[c1 + c]
                + w10 * r1[c0 + c] + w11 * r1[c1 + c];
        out[o + c] = v;
    }
}

extern "C" void kernel_launch(void* const* d_in, const int* in_sizes, int n_in,
                              void* d_out, int out_size, void* d_ws, size_t ws_size,
                              hipStream_t stream) {
    const float* img = (const float*)d_in[0];   // (2048,2048,3) f32
    const float* M   = (const float*)d_in[1];   // (3,3) f32 row-major
    float* out = (float*)d_out;                 // (2048,2048,3) f32

    dim3 grid((IMG_H * IMG_W) / 256), block(256);
    hipLaunchKernelGGL(affine_reflect_kernel, grid, block, 0, stream, img, M, out);
}